// Round 13
// baseline (119.291 us; speedup 1.0000x reference)
//
#include <hip/hip_runtime.h>
#include <hip/hip_bf16.h>

typedef __bf16 bf16_t;
typedef __bf16 bf16x2_t __attribute__((ext_vector_type(2)));
typedef __bf16 bf16x4_t __attribute__((ext_vector_type(4)));
typedef __bf16 bf16x8 __attribute__((ext_vector_type(8)));
typedef float f32x4 __attribute__((ext_vector_type(4)));
typedef float f32x16 __attribute__((ext_vector_type(16)));
typedef unsigned int u32x2 __attribute__((ext_vector_type(2)));

#define T_SEQ 1024
#define BATCH 8
#define NH 8
#define DH 128
#define HKDIM 1024  // NH*DH

static __device__ __forceinline__ f32x4 mfma16(bf16x8 a, bf16x8 b, f32x4 c) {
    return __builtin_amdgcn_mfma_f32_16x16x32_bf16(a, b, c, 0, 0, 0);
}
static __device__ __forceinline__ f32x16 mfma32(bf16x8 a, bf16x8 b, f32x16 c) {
    return __builtin_amdgcn_mfma_f32_32x32x16_bf16(a, b, c, 0, 0, 0);
}

// non-temporal stores: bypass L2 allocation (nt flag) so the big output
// streams don't evict the small shared operand sets.
static __device__ __forceinline__ void st_nt16(bf16_t* p, bf16x8 v) {
    __builtin_nontemporal_store(v, (bf16x8*)p);
}
static __device__ __forceinline__ void st_nt8(bf16_t* p, bf16x4_t v) {
    __builtin_nontemporal_store(v, (bf16x4_t*)p);
}

static __device__ __forceinline__ unsigned pk2(float a, float b) {
    bf16x2_t t;
    t[0] = (bf16_t)a;
    t[1] = (bf16_t)b;
    union { bf16x2_t v; unsigned u; } c;
    c.v = t;
    return c.u;
}

// v_permlane32_swap via builtin: r[0] = {a.lo, b.lo}, r[1] = {a.hi, b.hi}
static __device__ __forceinline__ void plswap(unsigned& a, unsigned& b) {
    u32x2 r = __builtin_amdgcn_permlane32_swap(a, b, false, false);
    a = r[0];
    b = r[1];
}

// value of x from lane^32 (pure VALU, no DS)
static __device__ __forceinline__ float swap_partner(float x) {
    u32x2 r = __builtin_amdgcn_permlane32_swap(__float_as_uint(x),
                                               __float_as_uint(x), false, false);
    return __uint_as_float((threadIdx.x & 32) ? r[0] : r[1]);
}

// ---------------------------------------------------------------------------
// Kernel 1: convert inputs to bf16 working layouts (float4-vectorized).
//   (Normal stores: xb/w3/wo are the small read-shared sets we WANT cached.)
// ---------------------------------------------------------------------------
__global__ __launch_bounds__(256) void convert_kernel(
        const float* __restrict__ x,
        const float* __restrict__ Wk, const float* __restrict__ Wq,
        const float* __restrict__ Wv, const float* __restrict__ Wo,
        bf16_t* __restrict__ xb, bf16_t* __restrict__ w3,
        bf16_t* __restrict__ wo) {
    const int n1 = T_SEQ * BATCH * DH;        // 1048576
    const int n2 = n1 + 3 * HKDIM * DH;       // +393216
    const int n3 = n2 + DH * HKDIM;           // +131072
    const int i = (blockIdx.x * 256 + threadIdx.x) * 4;
    if (i >= n3) return;
    const float* src;
    bf16_t* dst;
    if (i < n1) {
        int d = i & 127, t = (i >> 7) & 1023, b = i >> 17;
        src = x + (t * BATCH + b) * DH + d;
        dst = xb + i;
    } else if (i < n2) {
        int j = i - n1;
        int p = j >> 17;
        const float* W = (p == 0) ? Wk : (p == 1 ? Wq : Wv);
        src = W + (j & 131071);
        dst = w3 + j;
    } else {
        int j = i - n2;
        src = Wo + j;
        dst = wo + j;
    }
    f32x4 v = *(const f32x4*)src;
    bf16x4_t o;
    o[0] = (bf16_t)v[0]; o[1] = (bf16_t)v[1];
    o[2] = (bf16_t)v[2]; o[3] = (bf16_t)v[3];
    *(bf16x4_t*)dst = o;
}

// ---------------------------------------------------------------------------
// Kernel 2: QKV projection, 128-row blocks. Identical to r12 EXCEPT all
//   global output stores are non-temporal: the 50MB output stream was
//   write-allocating in the 4MiB per-XCD L2 and evicting the 2.75MB xb/w3
//   operand set, turning every operand read into an L3 round trip.
// ---------------------------------------------------------------------------
__global__ __launch_bounds__(256) void proj_kernel(
        const bf16_t* __restrict__ xb, const bf16_t* __restrict__ w3,
        const float* __restrict__ bk, const float* __restrict__ bq,
        const float* __restrict__ bv,
        bf16_t* __restrict__ kbuf, bf16_t* __restrict__ qbuf,
        bf16_t* __restrict__ vtbuf) {
    const int lane = threadIdx.x & 63;
    const int wave = threadIdx.x >> 6;
    const int lr = lane & 15, lq = lane >> 4;
    const int rm_base = blockIdx.x * 128;
    const int cb0 = blockIdx.y * 64;
    const int p = cb0 >> 10;
    const int cw0 = cb0 & 1023;          // col within projection (0..960)
    const int h = cw0 >> 7;
    const int dbase = cw0 & 127;         // 0 or 64
    const bool isV = (p == 2);

    __shared__ bf16_t sL[17408 / 2];     // union: aL[128][68] / vL[64][136]

    // A fragments: 8 loads, all in flight
    bf16x8 aF[2][4];
#pragma unroll
    for (int rg = 0; rg < 2; ++rg) {
        const int row = rm_base + rg * 64 + wave * 16 + lr;
#pragma unroll
        for (int kc = 0; kc < 4; ++kc)
            aF[rg][kc] = *(const bf16x8*)(xb + (size_t)row * DH + kc * 32 + lq * 8);
    }

    const bf16_t* wbase = w3 + (size_t)(cb0 + lr) * DH + lq * 8;
    bf16x8 kcur[4], knxt[4];
#pragma unroll
    for (int kc = 0; kc < 4; ++kc)
        kcur[kc] = *(const bf16x8*)(wbase + kc * 32);

    const float* bias_kq = (p == 0) ? bk : bq;
    bf16_t* dst = (p == 0) ? kbuf : qbuf;

    bf16_t (*aL)[68] = (bf16_t(*)[68])sL;
    bf16_t (*vL)[136] = (bf16_t(*)[136])sL;

#pragma unroll
    for (int nc = 0; nc < 4; ++nc) {
        // prefetch next nc's 4 W-fragments (completes under this nc's MFMAs)
        if (nc < 3) {
            const bf16_t* wn = wbase + (size_t)(nc + 1) * 16 * DH;
#pragma unroll
            for (int kc = 0; kc < 4; ++kc)
                knxt[kc] = *(const bf16x8*)(wn + kc * 32);
        }

        f32x4 acc[2] = {{0.f, 0.f, 0.f, 0.f}, {0.f, 0.f, 0.f, 0.f}};
        if (!isV) {
            // C[m = w-col][n = x-row]: lane n=lr (t-row), m = lq*4+r (d, consec.)
#pragma unroll
            for (int rg = 0; rg < 2; ++rg)
#pragma unroll
                for (int kc = 0; kc < 4; ++kc)
                    acc[rg] = mfma16(kcur[kc], aF[rg][kc], acc[rg]);

            const f32x4 b4 = *(const f32x4*)(bias_kq + cw0 + nc * 16 + lq * 4);
#pragma unroll
            for (int rg = 0; rg < 2; ++rg) {
                bf16x4_t o4;
#pragma unroll
                for (int r = 0; r < 4; ++r)
                    o4[r] = (bf16_t)(acc[rg][r] + b4[r]);
                *(bf16x4_t*)&aL[rg * 64 + wave * 16 + lr][nc * 16 + lq * 4] = o4;
            }
        } else {
            // C[m = x-row][n = w-col]: lane n=lr (d), m = lq*4+r (t)
#pragma unroll
            for (int rg = 0; rg < 2; ++rg)
#pragma unroll
                for (int kc = 0; kc < 4; ++kc)
                    acc[rg] = mfma16(aF[rg][kc], kcur[kc], acc[rg]);

            const float bias = bv[cw0 + nc * 16 + lr];
#pragma unroll
            for (int rg = 0; rg < 2; ++rg)
#pragma unroll
                for (int r = 0; r < 4; ++r)
                    vL[nc * 16 + lr][rg * 64 + wave * 16 + lq * 4 + r] =
                        (bf16_t)(acc[rg][r] + bias);
        }
        if (nc < 3) {
#pragma unroll
            for (int kc = 0; kc < 4; ++kc) kcur[kc] = knxt[kc];
        }
    }

    __syncthreads();
    const int tid = threadIdx.x;
    if (!isV) {
        // readout: 4 passes x 32 t-rows; 8 lanes cover one row's 128B half.
        const int tr = tid >> 3;            // 0..31
        const int d16 = tid & 7;            // 16B chunk within 64-d half
#pragma unroll
        for (int ps = 0; ps < 4; ++ps) {
            const int t_local = ps * 32 + tr;
            const int row = rm_base + t_local;
            const int bb = row >> 10, tt = row & 1023;
            bf16x8 v = *(const bf16x8*)&aL[t_local][d16 * 8];
            st_nt16(dst + ((size_t)(bb * NH + h) * T_SEQ + tt) * DH +
                    dbase + d16 * 8, v);
        }
    } else {
        // write out: 64 d-rows x 128 t, 64 B per thread, coalesced
        const int dl = tid >> 2;             // 0..63
        const int toff = (tid & 3) * 32;     // elements within the 128-t row
        const int bb = blockIdx.x >> 3;
        const int t0 = (blockIdx.x & 7) * 128;
        const int dg = dbase + dl;
        bf16_t* dstv = vtbuf + ((size_t)(bb * NH + h) * DH + dg) * T_SEQ + t0 + toff;
#pragma unroll
        for (int i = 0; i < 4; ++i)
            st_nt16(dstv + i * 8, *(const bf16x8*)&vL[dl][toff + i * 8]);
    }
}

// ---------------------------------------------------------------------------
// Kernel 3: flash attention, 128-row i-tile per block, KVBLK=64 LDS staging
//   with async-stage prefetch (T14), CU-pairing grid remap. obuf stores
//   now non-temporal (16MB stream; protects K/Q/V tiles in L2).
// ---------------------------------------------------------------------------
__global__ __launch_bounds__(256, 2) void attn_kernel(
        const bf16_t* __restrict__ kbuf, const bf16_t* __restrict__ qbuf,
        const bf16_t* __restrict__ vtb, bf16_t* __restrict__ obuf) {
    const int bx = blockIdx.x;
    const int T = (bx < 256) ? (7 - (bx >> 6)) : ((bx - 256) >> 6);
    const int bh = bx & 63;
    const int b = bh >> 3, h = bh & 7;
    const int wv = threadIdx.x >> 6;     // i-subtile 0..3
    const int lane = threadIdx.x & 63;
    const int li = lane & 31;
    const int hi = lane >> 5;
    const int i0 = T * 128 + wv * 32;    // wave's first row
    const int cmax = 4 * T + wv;         // last 32-chunk this wave computes
    const int nrounds = 2 * T + 2;       // 64-wide staging rounds

    const bf16_t* Qp = kbuf + (size_t)bh * T_SEQ * DH;  // rows i (key positions)
    const bf16_t* Kp = qbuf + (size_t)bh * T_SEQ * DH;  // cols j (query positions)
    const bf16_t* Vt = vtb + (size_t)bh * DH * T_SEQ;   // [d][t]

    __shared__ bf16_t kL[64][136];   // K super-chunk [j 0..63][d], 272B rows
    __shared__ bf16_t vL[128][72];   // V^T super-chunk [d][t 0..63], 144B rows

    // persistent Q B-fragments: lane: i=li, k = s*16 + hi*8 + e
    bf16x8 qf[8];
#pragma unroll
    for (int s = 0; s < 8; ++s)
        qf[s] = *(const bf16x8*)(Qp + (size_t)(i0 + li) * DH + s * 16 + hi * 8);

    f32x16 oacc[4];
#pragma unroll
    for (int c = 0; c < 4; ++c)
#pragma unroll
        for (int e = 0; e < 16; ++e) oacc[c][e] = 0.f;

    float m = 0.f, l = 0.f;
    const float C = 0.08838834764831845f * 1.4426950408889634f;  // scale*log2e

    // staging decomposition: 64B K + 64B V per thread per round
    const int tid = threadIdx.x;
    const int krow = tid >> 2;            // 0..63
    const int kcol = (tid & 3) * 32;      // 0,32,64,96
    const int vrow = tid >> 1;            // 0..127
    const int vcol = (tid & 1) * 32;      // 0,32
    const bf16_t* kgsrc = Kp + (size_t)krow * DH + kcol;
    const bf16_t* vgsrc = Vt + (size_t)vrow * T_SEQ + vcol;

    // prologue: load round 0 into registers
    bf16x8 kr[4], vr[4];
#pragma unroll
    for (int i = 0; i < 4; ++i) {
        kr[i] = *(const bf16x8*)(kgsrc + i * 8);
        vr[i] = *(const bf16x8*)(vgsrc + i * 8);
    }

    for (int rd = 0; rd < nrounds; ++rd) {
        __syncthreads();   // previous round's readers done
#pragma unroll
        for (int i = 0; i < 4; ++i) {
            *(bf16x8*)&kL[krow][kcol + i * 8] = kr[i];
            *(bf16x8*)&vL[vrow][vcol + i * 8] = vr[i];
        }
        // T14: issue next round's global loads now; they complete under
        // this round's compute and are consumed after the next barrier.
        if (rd + 1 < nrounds) {
            const bf16_t* kn = kgsrc + (size_t)(rd + 1) * 64 * DH;
            const bf16_t* vn = vgsrc + (size_t)(rd + 1) * 64;
#pragma unroll
            for (int i = 0; i < 4; ++i) {
                kr[i] = *(const bf16x8*)(kn + i * 8);
                vr[i] = *(const bf16x8*)(vn + i * 8);
            }
        }
        __syncthreads();   // LDS for this round ready

#pragma unroll
        for (int jj = 0; jj < 2; ++jj) {
            const int c32 = rd * 2 + jj;
            if (c32 > cmax) continue;

            // K fragments from LDS
            bf16x8 ka[8];
#pragma unroll
            for (int s = 0; s < 8; ++s)
                ka[s] = *(const bf16x8*)&kL[jj * 32 + li][s * 16 + hi * 8];

            // S^T = K' Q'^T : C[m=j][n=i]
            f32x16 sc;
#pragma unroll
            for (int e = 0; e < 16; ++e) sc[e] = 0.f;
            __builtin_amdgcn_s_setprio(1);
#pragma unroll
            for (int s = 0; s < 8; ++s) sc = mfma32(ka[s], qf[s], sc);
            __builtin_amdgcn_s_setprio(0);

            // scale (+ diagonal causal mask: j > i)
            f32x16 sv;
#pragma unroll
            for (int e = 0; e < 16; ++e) sv[e] = sc[e] * C;
            if (c32 == cmax) {
#pragma unroll
                for (int r = 0; r < 16; ++r) {
                    const int jrow = (r & 3) + 8 * (r >> 2) + 4 * hi;
                    if (jrow > li) sv[r] = -1e30f;
                }
            }

            // row max: in-lane tree + cross-half permlane (no DS)
            float pm = sv[0];
#pragma unroll
            for (int r = 1; r < 16; ++r) pm = fmaxf(pm, sv[r]);
            pm = fmaxf(pm, swap_partner(pm));

            // T13 defer-rescale (log2 domain, THR=8)
            if (!__all(pm <= m + 8.f)) {
                const float mn = fmaxf(m, pm);
                const float f = exp2f(m - mn);
                m = mn;
                l *= f;
#pragma unroll
                for (int cc = 0; cc < 4; ++cc)
#pragma unroll
                    for (int e = 0; e < 16; ++e) oacc[cc][e] *= f;
            }

            // P = 2^(sv - m), pack to bf16 pairs along j
            float ls = 0.f;
            unsigned Wp[8];
#pragma unroll
            for (int q = 0; q < 4; ++q) {
                const float p0 = exp2f(sv[4 * q + 0] - m);
                const float p1 = exp2f(sv[4 * q + 1] - m);
                const float p2 = exp2f(sv[4 * q + 2] - m);
                const float p3 = exp2f(sv[4 * q + 3] - m);
                ls += (p0 + p1) + (p2 + p3);
                Wp[2 * q] = pk2(p0, p1);
                Wp[2 * q + 1] = pk2(p2, p3);
            }
            l += ls;

            // redistribute P into B-fragments: 4 permlane32_swap (pure VALU)
            plswap(Wp[0], Wp[2]);
            plswap(Wp[1], Wp[3]);
            plswap(Wp[4], Wp[6]);
            plswap(Wp[5], Wp[7]);
            union { unsigned u[4]; bf16x8 v; } pb0, pb1;
            pb0.u[0] = Wp[0]; pb0.u[1] = Wp[1]; pb0.u[2] = Wp[2]; pb0.u[3] = Wp[3];
            pb1.u[0] = Wp[4]; pb1.u[1] = Wp[5]; pb1.u[2] = Wp[6]; pb1.u[3] = Wp[7];

            // V fragments from LDS; PV: O^T[d][i] += V^T[d][j] P[j][i]
            bf16x8 va[8];
#pragma unroll
            for (int n = 0; n < 4; ++n) {
                va[2 * n]     = *(const bf16x8*)&vL[li + 32 * n][jj * 32 + hi * 8];
                va[2 * n + 1] = *(const bf16x8*)&vL[li + 32 * n][jj * 32 + hi * 8 + 16];
            }
            __builtin_amdgcn_s_setprio(1);
            oacc[0] = mfma32(va[0], pb0.v, oacc[0]);
            oacc[0] = mfma32(va[1], pb1.v, oacc[0]);
            oacc[1] = mfma32(va[2], pb0.v, oacc[1]);
            oacc[1] = mfma32(va[3], pb1.v, oacc[1]);
            oacc[2] = mfma32(va[4], pb0.v, oacc[2]);
            oacc[2] = mfma32(va[5], pb1.v, oacc[2]);
            oacc[3] = mfma32(va[6], pb0.v, oacc[3]);
            oacc[3] = mfma32(va[7], pb1.v, oacc[3]);
            __builtin_amdgcn_s_setprio(0);
        }
    }

    // epilogue: each wave owns complete rows — normalize and store directly
    const float lfull = l + swap_partner(l);
    const float inv = 1.f / lfull;
    bf16_t* orow = obuf + ((size_t)b * T_SEQ + i0 + li) * HKDIM + h * DH;
#pragma unroll
    for (int c = 0; c < 4; ++c)
#pragma unroll
        for (int q = 0; q < 4; ++q) {
            bf16x4_t o4;
#pragma unroll
            for (int rr = 0; rr < 4; ++rr)
                o4[rr] = (bf16_t)(oacc[c][4 * q + rr] * inv);
            st_nt8(orow + c * 32 + q * 8 + 4 * hi, o4);
        }
}

// ---------------------------------------------------------------------------
// Kernel 4: output projection, split-K over waves; out stores non-temporal.
// ---------------------------------------------------------------------------
__global__ __launch_bounds__(256) void outproj_kernel(
        const bf16_t* __restrict__ obuf, const bf16_t* __restrict__ wo,
        const float* __restrict__ bo, float* __restrict__ out) {
    const int lane = threadIdx.x & 63, wave = threadIdx.x >> 6;
    const int lr = lane & 15, lq = lane >> 4;
    const int rm0 = blockIdx.x * 16;
    __shared__ float red[4][8][256];   // [wave][g][lane*4]

    f32x4 acc[8];
#pragma unroll
    for (int g = 0; g < 8; ++g) acc[g] = {0.f, 0.f, 0.f, 0.f};
#pragma unroll 2
    for (int k8 = 0; k8 < 8; ++k8) {
        const int kc = wave * 8 + k8;
        bf16x8 aF = *(const bf16x8*)(obuf + (size_t)(rm0 + lr) * HKDIM + kc * 32 + lq * 8);
#pragma unroll
        for (int g = 0; g < 8; ++g) {
            bf16x8 bF = *(const bf16x8*)(wo + (size_t)(g * 16 + lr) * HKDIM + kc * 32 + lq * 8);
            acc[g] = mfma16(aF, bF, acc[g]);
        }
    }
#pragma unroll
    for (int g = 0; g < 8; ++g)
        *(f32x4*)&red[wave][g][lane * 4] = acc[g];
    __syncthreads();
#pragma unroll
    for (int gi = 0; gi < 2; ++gi) {
        const int g = wave * 2 + gi;
        f32x4 s = *(const f32x4*)&red[0][g][lane * 4];
#pragma unroll
        for (int w = 1; w < 4; ++w) {
            f32x4 t = *(const f32x4*)&red[w][g][lane * 4];
            s[0] += t[0]; s[1] += t[1]; s[2] += t[2]; s[3] += t[3];
        }
        const int col = g * 16 + lr;
        const float bias = bo[col];
#pragma unroll
        for (int r = 0; r < 4; ++r) {
            const int row = rm0 + lq * 4 + r;
            const int bb = row >> 10, tt = row & 1023;
            __builtin_nontemporal_store(
                s[r] + bias, &out[((size_t)tt * BATCH + bb) * DH + col]);
        }
    }
}

// ---------------------------------------------------------------------------
extern "C" void kernel_launch(void* const* d_in, const int* in_sizes, int n_in,
                              void* d_out, int out_size, void* d_ws, size_t ws_size,
                              hipStream_t stream) {
    const float* x  = (const float*)d_in[0];
    const float* Wk = (const float*)d_in[1];
    const float* bk = (const float*)d_in[2];
    const float* Wq = (const float*)d_in[3];
    const float* bq = (const float*)d_in[4];
    const float* Wv = (const float*)d_in[5];
    const float* bv = (const float*)d_in[6];
    const float* Wo = (const float*)d_in[7];
    const float* bo = (const float*)d_in[8];
    float* out = (float*)d_out;

    char* ws = (char*)d_ws;
    size_t off = 0;
    bf16_t* xb  = (bf16_t*)(ws + off); off += (size_t)BATCH * T_SEQ * DH * 2;       // 2 MiB
    bf16_t* w3  = (bf16_t*)(ws + off); off += (size_t)3 * HKDIM * DH * 2;           // 0.75 MiB
    bf16_t* wo  = (bf16_t*)(ws + off); off += (size_t)DH * HKDIM * 2;               // 0.25 MiB
    bf16_t* kb  = (bf16_t*)(ws + off); off += (size_t)BATCH * NH * T_SEQ * DH * 2;  // 16 MiB
    bf16_t* qb  = (bf16_t*)(ws + off); off += (size_t)BATCH * NH * T_SEQ * DH * 2;  // 16 MiB
    bf16_t* vtb = (bf16_t*)(ws + off); off += (size_t)BATCH * NH * T_SEQ * DH * 2;  // 16 MiB
    bf16_t* ob  = (bf16_t*)(ws + off); off += (size_t)BATCH * T_SEQ * HKDIM * 2;    // 16 MiB

    convert_kernel<<<1536, 256, 0, stream>>>(x, Wk, Wq, Wv, Wo, xb, w3, wo);
    proj_kernel<<<dim3(64, 48), 256, 0, stream>>>(xb, w3, bk, bq, bv, kb, qb, vtb);
    attn_kernel<<<512, 256, 0, stream>>>(kb, qb, vtb, ob);
    outproj_kernel<<<512, 256, 0, stream>>>(ob, wo, bo, out);
}

// Round 14
// 100.240 us; speedup vs baseline: 1.1901x; 1.1901x over previous
//
#include <hip/hip_runtime.h>
#include <hip/hip_bf16.h>

typedef __bf16 bf16_t;
typedef __bf16 bf16x2_t __attribute__((ext_vector_type(2)));
typedef __bf16 bf16x4_t __attribute__((ext_vector_type(4)));
typedef __bf16 bf16x8 __attribute__((ext_vector_type(8)));
typedef float f32x4 __attribute__((ext_vector_type(4)));
typedef float f32x16 __attribute__((ext_vector_type(16)));
typedef unsigned int u32x2 __attribute__((ext_vector_type(2)));

#define T_SEQ 1024
#define BATCH 8
#define NH 8
#define DH 128
#define HKDIM 1024  // NH*DH

static __device__ __forceinline__ f32x4 mfma16(bf16x8 a, bf16x8 b, f32x4 c) {
    return __builtin_amdgcn_mfma_f32_16x16x32_bf16(a, b, c, 0, 0, 0);
}
static __device__ __forceinline__ f32x16 mfma32(bf16x8 a, bf16x8 b, f32x16 c) {
    return __builtin_amdgcn_mfma_f32_32x32x16_bf16(a, b, c, 0, 0, 0);
}

static __device__ __forceinline__ unsigned pk2(float a, float b) {
    bf16x2_t t;
    t[0] = (bf16_t)a;
    t[1] = (bf16_t)b;
    union { bf16x2_t v; unsigned u; } c;
    c.v = t;
    return c.u;
}

// v_permlane32_swap via builtin: r[0] = {a.lo, b.lo}, r[1] = {a.hi, b.hi}
static __device__ __forceinline__ void plswap(unsigned& a, unsigned& b) {
    u32x2 r = __builtin_amdgcn_permlane32_swap(a, b, false, false);
    a = r[0];
    b = r[1];
}

// value of x from lane^32 (pure VALU, no DS)
static __device__ __forceinline__ float swap_partner(float x) {
    u32x2 r = __builtin_amdgcn_permlane32_swap(__float_as_uint(x),
                                               __float_as_uint(x), false, false);
    return __uint_as_float((threadIdx.x & 32) ? r[0] : r[1]);
}

// ---------------------------------------------------------------------------
// Kernel 1: convert inputs to bf16 working layouts (float4-vectorized).
// ---------------------------------------------------------------------------
__global__ __launch_bounds__(256) void convert_kernel(
        const float* __restrict__ x,
        const float* __restrict__ Wk, const float* __restrict__ Wq,
        const float* __restrict__ Wv, const float* __restrict__ Wo,
        bf16_t* __restrict__ xb, bf16_t* __restrict__ w3,
        bf16_t* __restrict__ wo) {
    const int n1 = T_SEQ * BATCH * DH;        // 1048576
    const int n2 = n1 + 3 * HKDIM * DH;       // +393216
    const int n3 = n2 + DH * HKDIM;           // +131072
    const int i = (blockIdx.x * 256 + threadIdx.x) * 4;
    if (i >= n3) return;
    const float* src;
    bf16_t* dst;
    if (i < n1) {
        int d = i & 127, t = (i >> 7) & 1023, b = i >> 17;
        src = x + (t * BATCH + b) * DH + d;
        dst = xb + i;
    } else if (i < n2) {
        int j = i - n1;
        int p = j >> 17;
        const float* W = (p == 0) ? Wk : (p == 1 ? Wq : Wv);
        src = W + (j & 131071);
        dst = w3 + j;
    } else {
        int j = i - n2;
        src = Wo + j;
        dst = wo + j;
    }
    f32x4 v = *(const f32x4*)src;
    bf16x4_t o;
    o[0] = (bf16_t)v[0]; o[1] = (bf16_t)v[1];
    o[2] = (bf16_t)v[2]; o[3] = (bf16_t)v[3];
    *(bf16x4_t*)dst = o;
}

// ---------------------------------------------------------------------------
// Kernel 2: QKV projection. One block = 128 rows x ONE FULL HEAD (128 d).
//   All global output stores are now 256B-CONTIGUOUS per row (full DRAM
//   bursts): r8-r13 showed proj duration tracks HBM write efficiency, and
//   64-d-wide tiles left every 256B line half-written (~1.2 TB/s cap).
//   Grid: dim3(64, 24); by: p = by>>3 (K/Q/V), h = by&7.
//   K/Q: swapped operand order (W as A) -> lane holds t-row, d consecutive;
//   staged in LDS, read out as 16B x 16 lanes = 256B/row. V: LDS transpose
//   to [bh][d][t]; each d-row is 256B contiguous.
// ---------------------------------------------------------------------------
__global__ __launch_bounds__(256) void proj_kernel(
        const bf16_t* __restrict__ xb, const bf16_t* __restrict__ w3,
        const float* __restrict__ bk, const float* __restrict__ bq,
        const float* __restrict__ bv,
        bf16_t* __restrict__ kbuf, bf16_t* __restrict__ qbuf,
        bf16_t* __restrict__ vtbuf) {
    const int lane = threadIdx.x & 63;
    const int wave = threadIdx.x >> 6;
    const int lr = lane & 15, lq = lane >> 4;
    const int rm_base = blockIdx.x * 128;
    const int p = blockIdx.y >> 3;       // 0=K, 1=Q, 2=V
    const int h = blockIdx.y & 7;
    const int cb0 = p * 1024 + h * 128;  // global col of this head's d=0
    const int cw0 = h * 128;             // col within projection
    const bool isV = (p == 2);

    __shared__ bf16_t sL[128][136];      // aL[t][d] (K/Q) or vL[d][t] (V)

    // A fragments from xb: 8 loads in flight
    bf16x8 aF[2][4];
#pragma unroll
    for (int rg = 0; rg < 2; ++rg) {
        const int row = rm_base + rg * 64 + wave * 16 + lr;
#pragma unroll
        for (int kc = 0; kc < 4; ++kc)
            aF[rg][kc] = *(const bf16x8*)(xb + (size_t)row * DH + kc * 32 + lq * 8);
    }

    const bf16_t* wbase = w3 + (size_t)(cb0 + lr) * DH + lq * 8;
    bf16x8 kcur[4], knxt[4];
#pragma unroll
    for (int kc = 0; kc < 4; ++kc)
        kcur[kc] = *(const bf16x8*)(wbase + kc * 32);

    const float* bias_kq = (p == 0) ? bk : bq;
    bf16_t* dst = (p == 0) ? kbuf : qbuf;

#pragma unroll
    for (int nc = 0; nc < 8; ++nc) {
        if (nc < 7) {
            const bf16_t* wn = wbase + (size_t)(nc + 1) * 16 * DH;
#pragma unroll
            for (int kc = 0; kc < 4; ++kc)
                knxt[kc] = *(const bf16x8*)(wn + kc * 32);
        }

        f32x4 acc[2] = {{0.f, 0.f, 0.f, 0.f}, {0.f, 0.f, 0.f, 0.f}};
        if (!isV) {
            // C[m=w-col][n=x-row]: lane n=lr (t-row), m=lq*4+r (d, consecutive)
#pragma unroll
            for (int rg = 0; rg < 2; ++rg)
#pragma unroll
                for (int kc = 0; kc < 4; ++kc)
                    acc[rg] = mfma16(kcur[kc], aF[rg][kc], acc[rg]);

            const f32x4 b4 = *(const f32x4*)(bias_kq + cw0 + nc * 16 + lq * 4);
#pragma unroll
            for (int rg = 0; rg < 2; ++rg) {
                bf16x4_t o4;
#pragma unroll
                for (int r = 0; r < 4; ++r)
                    o4[r] = (bf16_t)(acc[rg][r] + b4[r]);
                *(bf16x4_t*)&sL[rg * 64 + wave * 16 + lr][nc * 16 + lq * 4] = o4;
            }
        } else {
            // C[m=x-row][n=w-col]: lane n=lr (d), m=lq*4+r (t)
#pragma unroll
            for (int rg = 0; rg < 2; ++rg)
#pragma unroll
                for (int kc = 0; kc < 4; ++kc)
                    acc[rg] = mfma16(aF[rg][kc], kcur[kc], acc[rg]);

            const float bias = bv[cw0 + nc * 16 + lr];
#pragma unroll
            for (int rg = 0; rg < 2; ++rg)
#pragma unroll
                for (int r = 0; r < 4; ++r)
                    sL[nc * 16 + lr][rg * 64 + wave * 16 + lq * 4 + r] =
                        (bf16_t)(acc[rg][r] + bias);
        }
        if (nc < 7) {
#pragma unroll
            for (int kc = 0; kc < 4; ++kc) kcur[kc] = knxt[kc];
        }
    }

    __syncthreads();
    const int tid = threadIdx.x;
    if (!isV) {
        // K/Q readout: 8 passes x 16 rows; 16 lanes cover a full 256B row.
        const int tr = tid >> 4;            // 0..15
        const int ck = tid & 15;            // 16B chunk
#pragma unroll
        for (int ps = 0; ps < 8; ++ps) {
            const int t_local = ps * 16 + tr;
            const int row = rm_base + t_local;
            const int bb = row >> 10, tt = row & 1023;
            bf16x8 v = *(const bf16x8*)&sL[t_local][ck * 8];
            *(bf16x8*)(dst + ((size_t)(bb * NH + h) * T_SEQ + tt) * DH + ck * 8) = v;
        }
    } else {
        // V readout: 8 passes x 16 d-rows; 16 lanes cover 256B (128 t) row.
        const int dr = tid >> 4;            // 0..15
        const int ck = tid & 15;            // 16B chunk within 128-t row
        const int bb = blockIdx.x >> 3;
        const int t0 = (blockIdx.x & 7) * 128;
#pragma unroll
        for (int ps = 0; ps < 8; ++ps) {
            const int d = ps * 16 + dr;
            bf16x8 v = *(const bf16x8*)&sL[d][ck * 8];
            *(bf16x8*)(vtbuf + ((size_t)(bb * NH + h) * DH + d) * T_SEQ +
                       t0 + ck * 8) = v;
        }
    }
}

// ---------------------------------------------------------------------------
// Kernel 3: flash attention, 128-row i-tile per block, KVBLK=64 LDS staging
//   with async-stage prefetch (T14), CU-pairing grid remap. Epilogue now
//   stages O through the (idle) kL buffer -> 16B stores, 16 lanes = 256B row.
// ---------------------------------------------------------------------------
__global__ __launch_bounds__(256, 2) void attn_kernel(
        const bf16_t* __restrict__ kbuf, const bf16_t* __restrict__ qbuf,
        const bf16_t* __restrict__ vtb, bf16_t* __restrict__ obuf) {
    const int bx = blockIdx.x;
    const int T = (bx < 256) ? (7 - (bx >> 6)) : ((bx - 256) >> 6);
    const int bh = bx & 63;
    const int b = bh >> 3, h = bh & 7;
    const int wv = threadIdx.x >> 6;     // i-subtile 0..3
    const int lane = threadIdx.x & 63;
    const int li = lane & 31;
    const int hi = lane >> 5;
    const int i0 = T * 128 + wv * 32;    // wave's first row
    const int cmax = 4 * T + wv;         // last 32-chunk this wave computes
    const int nrounds = 2 * T + 2;       // 64-wide staging rounds

    const bf16_t* Qp = kbuf + (size_t)bh * T_SEQ * DH;  // rows i (key positions)
    const bf16_t* Kp = qbuf + (size_t)bh * T_SEQ * DH;  // cols j (query positions)
    const bf16_t* Vt = vtb + (size_t)bh * DH * T_SEQ;   // [d][t]

    __shared__ bf16_t kL[64][136];   // K super-chunk [j 0..63][d], 272B rows
    __shared__ bf16_t vL[128][72];   // V^T super-chunk [d][t 0..63], 144B rows

    // persistent Q B-fragments: lane: i=li, k = s*16 + hi*8 + e
    bf16x8 qf[8];
#pragma unroll
    for (int s = 0; s < 8; ++s)
        qf[s] = *(const bf16x8*)(Qp + (size_t)(i0 + li) * DH + s * 16 + hi * 8);

    f32x16 oacc[4];
#pragma unroll
    for (int c = 0; c < 4; ++c)
#pragma unroll
        for (int e = 0; e < 16; ++e) oacc[c][e] = 0.f;

    float m = 0.f, l = 0.f;
    const float C = 0.08838834764831845f * 1.4426950408889634f;  // scale*log2e

    // staging decomposition: 64B K + 64B V per thread per round
    const int tid = threadIdx.x;
    const int krow = tid >> 2;            // 0..63
    const int kcol = (tid & 3) * 32;      // 0,32,64,96
    const int vrow = tid >> 1;            // 0..127
    const int vcol = (tid & 1) * 32;      // 0,32
    const bf16_t* kgsrc = Kp + (size_t)krow * DH + kcol;
    const bf16_t* vgsrc = Vt + (size_t)vrow * T_SEQ + vcol;

    // prologue: load round 0 into registers
    bf16x8 kr[4], vr[4];
#pragma unroll
    for (int i = 0; i < 4; ++i) {
        kr[i] = *(const bf16x8*)(kgsrc + i * 8);
        vr[i] = *(const bf16x8*)(vgsrc + i * 8);
    }

    for (int rd = 0; rd < nrounds; ++rd) {
        __syncthreads();   // previous round's readers done
#pragma unroll
        for (int i = 0; i < 4; ++i) {
            *(bf16x8*)&kL[krow][kcol + i * 8] = kr[i];
            *(bf16x8*)&vL[vrow][vcol + i * 8] = vr[i];
        }
        // T14: issue next round's global loads now; they complete under
        // this round's compute and are consumed after the next barrier.
        if (rd + 1 < nrounds) {
            const bf16_t* kn = kgsrc + (size_t)(rd + 1) * 64 * DH;
            const bf16_t* vn = vgsrc + (size_t)(rd + 1) * 64;
#pragma unroll
            for (int i = 0; i < 4; ++i) {
                kr[i] = *(const bf16x8*)(kn + i * 8);
                vr[i] = *(const bf16x8*)(vn + i * 8);
            }
        }
        __syncthreads();   // LDS for this round ready

#pragma unroll
        for (int jj = 0; jj < 2; ++jj) {
            const int c32 = rd * 2 + jj;
            if (c32 > cmax) continue;

            // K fragments from LDS
            bf16x8 ka[8];
#pragma unroll
            for (int s = 0; s < 8; ++s)
                ka[s] = *(const bf16x8*)&kL[jj * 32 + li][s * 16 + hi * 8];

            // S^T = K' Q'^T : C[m=j][n=i]
            f32x16 sc;
#pragma unroll
            for (int e = 0; e < 16; ++e) sc[e] = 0.f;
            __builtin_amdgcn_s_setprio(1);
#pragma unroll
            for (int s = 0; s < 8; ++s) sc = mfma32(ka[s], qf[s], sc);
            __builtin_amdgcn_s_setprio(0);

            // scale (+ diagonal causal mask: j > i)
            f32x16 sv;
#pragma unroll
            for (int e = 0; e < 16; ++e) sv[e] = sc[e] * C;
            if (c32 == cmax) {
#pragma unroll
                for (int r = 0; r < 16; ++r) {
                    const int jrow = (r & 3) + 8 * (r >> 2) + 4 * hi;
                    if (jrow > li) sv[r] = -1e30f;
                }
            }

            // row max: in-lane tree + cross-half permlane (no DS)
            float pm = sv[0];
#pragma unroll
            for (int r = 1; r < 16; ++r) pm = fmaxf(pm, sv[r]);
            pm = fmaxf(pm, swap_partner(pm));

            // T13 defer-rescale (log2 domain, THR=8)
            if (!__all(pm <= m + 8.f)) {
                const float mn = fmaxf(m, pm);
                const float f = exp2f(m - mn);
                m = mn;
                l *= f;
#pragma unroll
                for (int cc = 0; cc < 4; ++cc)
#pragma unroll
                    for (int e = 0; e < 16; ++e) oacc[cc][e] *= f;
            }

            // P = 2^(sv - m), pack to bf16 pairs along j
            float ls = 0.f;
            unsigned Wp[8];
#pragma unroll
            for (int q = 0; q < 4; ++q) {
                const float p0 = exp2f(sv[4 * q + 0] - m);
                const float p1 = exp2f(sv[4 * q + 1] - m);
                const float p2 = exp2f(sv[4 * q + 2] - m);
                const float p3 = exp2f(sv[4 * q + 3] - m);
                ls += (p0 + p1) + (p2 + p3);
                Wp[2 * q] = pk2(p0, p1);
                Wp[2 * q + 1] = pk2(p2, p3);
            }
            l += ls;

            // redistribute P into B-fragments: 4 permlane32_swap (pure VALU)
            plswap(Wp[0], Wp[2]);
            plswap(Wp[1], Wp[3]);
            plswap(Wp[4], Wp[6]);
            plswap(Wp[5], Wp[7]);
            union { unsigned u[4]; bf16x8 v; } pb0, pb1;
            pb0.u[0] = Wp[0]; pb0.u[1] = Wp[1]; pb0.u[2] = Wp[2]; pb0.u[3] = Wp[3];
            pb1.u[0] = Wp[4]; pb1.u[1] = Wp[5]; pb1.u[2] = Wp[6]; pb1.u[3] = Wp[7];

            // V fragments from LDS; PV: O^T[d][i] += V^T[d][j] P[j][i]
            bf16x8 va[8];
#pragma unroll
            for (int n = 0; n < 4; ++n) {
                va[2 * n]     = *(const bf16x8*)&vL[li + 32 * n][jj * 32 + hi * 8];
                va[2 * n + 1] = *(const bf16x8*)&vL[li + 32 * n][jj * 32 + hi * 8 + 16];
            }
            __builtin_amdgcn_s_setprio(1);
            oacc[0] = mfma32(va[0], pb0.v, oacc[0]);
            oacc[0] = mfma32(va[1], pb1.v, oacc[0]);
            oacc[1] = mfma32(va[2], pb0.v, oacc[1]);
            oacc[1] = mfma32(va[3], pb1.v, oacc[1]);
            oacc[2] = mfma32(va[4], pb0.v, oacc[2]);
            oacc[2] = mfma32(va[5], pb1.v, oacc[2]);
            oacc[3] = mfma32(va[6], pb0.v, oacc[3]);
            oacc[3] = mfma32(va[7], pb1.v, oacc[3]);
            __builtin_amdgcn_s_setprio(0);
        }
    }

    // epilogue: normalize, stage O rows in LDS (kL reused), then write each
    // 128-row x 256B obuf row with 16 lanes x 16B (full-line bursts).
    const float lfull = l + swap_partner(l);
    const float inv = 1.f / lfull;
    __syncthreads();   // staging LDS free
    bf16_t (*oL)[136] = (bf16_t(*)[136])kL;   // 32 rows per wave quadrant? use 128x136 view across kL+vL? kL is [64][136] = 64 rows.
    // waves 0,1 use kL rows 0..63; waves 2,3 use vL area via pointer arith.
    bf16_t* base = (wv < 2) ? &kL[0][0] : &vL[0][0];
    const int rloc = (wv & 1) * 32 + li;      // row within this buffer half
#pragma unroll
    for (int c = 0; c < 4; ++c)
#pragma unroll
        for (int q = 0; q < 4; ++q) {
            bf16x4_t o4;
#pragma unroll
            for (int rr = 0; rr < 4; ++rr)
                o4[rr] = (bf16_t)(oacc[c][4 * q + rr] * inv);
            *(bf16x4_t*)(base + (size_t)rloc * 136 + c * 32 + q * 8 + 4 * hi) = o4;
        }
    __syncthreads();
    // write out: 128 rows x 256B; thread tid covers (row = tid>>4 within
    // 16-row group per pass, chunk = tid&15)
    {
        const int tr = tid >> 4;   // 0..15
        const int ck = tid & 15;
#pragma unroll
        for (int ps = 0; ps < 8; ++ps) {
            const int rl = ps * 16 + tr;           // 0..127
            const bf16_t* src = ((rl & 64) ? &vL[0][0] : &kL[0][0]) +
                                (size_t)(rl & 63) * 136 + ck * 8;
            bf16x8 v = *(const bf16x8*)src;
            const int row = T * 128 + rl;
            *(bf16x8*)(obuf + ((size_t)b * T_SEQ + row) * HKDIM + h * DH + ck * 8) = v;
        }
    }
}

// ---------------------------------------------------------------------------
// Kernel 4: output projection, split-K over waves (normal stores).
// ---------------------------------------------------------------------------
__global__ __launch_bounds__(256) void outproj_kernel(
        const bf16_t* __restrict__ obuf, const bf16_t* __restrict__ wo,
        const float* __restrict__ bo, float* __restrict__ out) {
    const int lane = threadIdx.x & 63, wave = threadIdx.x >> 6;
    const int lr = lane & 15, lq = lane >> 4;
    const int rm0 = blockIdx.x * 16;
    __shared__ float red[4][8][256];   // [wave][g][lane*4]

    f32x4 acc[8];
#pragma unroll
    for (int g = 0; g < 8; ++g) acc[g] = {0.f, 0.f, 0.f, 0.f};
#pragma unroll 2
    for (int k8 = 0; k8 < 8; ++k8) {
        const int kc = wave * 8 + k8;
        bf16x8 aF = *(const bf16x8*)(obuf + (size_t)(rm0 + lr) * HKDIM + kc * 32 + lq * 8);
#pragma unroll
        for (int g = 0; g < 8; ++g) {
            bf16x8 bF = *(const bf16x8*)(wo + (size_t)(g * 16 + lr) * HKDIM + kc * 32 + lq * 8);
            acc[g] = mfma16(aF, bF, acc[g]);
        }
    }
#pragma unroll
    for (int g = 0; g < 8; ++g)
        *(f32x4*)&red[wave][g][lane * 4] = acc[g];
    __syncthreads();
#pragma unroll
    for (int gi = 0; gi < 2; ++gi) {
        const int g = wave * 2 + gi;
        f32x4 s = *(const f32x4*)&red[0][g][lane * 4];
#pragma unroll
        for (int w = 1; w < 4; ++w) {
            f32x4 t = *(const f32x4*)&red[w][g][lane * 4];
            s[0] += t[0]; s[1] += t[1]; s[2] += t[2]; s[3] += t[3];
        }
        const int col = g * 16 + lr;
        const float bias = bo[col];
#pragma unroll
        for (int r = 0; r < 4; ++r) {
            const int row = rm0 + lq * 4 + r;
            const int bb = row >> 10, tt = row & 1023;
            out[((size_t)tt * BATCH + bb) * DH + col] = s[r] + bias;
        }
    }
}

// ---------------------------------------------------------------------------
extern "C" void kernel_launch(void* const* d_in, const int* in_sizes, int n_in,
                              void* d_out, int out_size, void* d_ws, size_t ws_size,
                              hipStream_t stream) {
    const float* x  = (const float*)d_in[0];
    const float* Wk = (const float*)d_in[1];
    const float* bk = (const float*)d_in[2];
    const float* Wq = (const float*)d_in[3];
    const float* bq = (const float*)d_in[4];
    const float* Wv = (const float*)d_in[5];
    const float* bv = (const float*)d_in[6];
    const float* Wo = (const float*)d_in[7];
    const float* bo = (const float*)d_in[8];
    float* out = (float*)d_out;

    char* ws = (char*)d_ws;
    size_t off = 0;
    bf16_t* xb  = (bf16_t*)(ws + off); off += (size_t)BATCH * T_SEQ * DH * 2;       // 2 MiB
    bf16_t* w3  = (bf16_t*)(ws + off); off += (size_t)3 * HKDIM * DH * 2;           // 0.75 MiB
    bf16_t* wo  = (bf16_t*)(ws + off); off += (size_t)DH * HKDIM * 2;               // 0.25 MiB
    bf16_t* kb  = (bf16_t*)(ws + off); off += (size_t)BATCH * NH * T_SEQ * DH * 2;  // 16 MiB
    bf16_t* qb  = (bf16_t*)(ws + off); off += (size_t)BATCH * NH * T_SEQ * DH * 2;  // 16 MiB
    bf16_t* vtb = (bf16_t*)(ws + off); off += (size_t)BATCH * NH * T_SEQ * DH * 2;  // 16 MiB
    bf16_t* ob  = (bf16_t*)(ws + off); off += (size_t)BATCH * T_SEQ * HKDIM * 2;    // 16 MiB

    convert_kernel<<<1536, 256, 0, stream>>>(x, Wk, Wq, Wv, Wo, xb, w3, wo);
    proj_kernel<<<dim3(64, 24), 256, 0, stream>>>(xb, w3, bk, bq, bv, kb, qb, vtb);
    attn_kernel<<<512, 256, 0, stream>>>(kb, qb, vtb, ob);
    outproj_kernel<<<512, 256, 0, stream>>>(ob, wo, bo, out);
}

// Round 15
// 94.636 us; speedup vs baseline: 1.2605x; 1.0592x over previous
//
#include <hip/hip_runtime.h>
#include <hip/hip_bf16.h>

typedef __bf16 bf16_t;
typedef __bf16 bf16x2_t __attribute__((ext_vector_type(2)));
typedef __bf16 bf16x4_t __attribute__((ext_vector_type(4)));
typedef __bf16 bf16x8 __attribute__((ext_vector_type(8)));
typedef float f32x4 __attribute__((ext_vector_type(4)));
typedef float f32x16 __attribute__((ext_vector_type(16)));
typedef unsigned int u32x2 __attribute__((ext_vector_type(2)));

#define T_SEQ 1024
#define BATCH 8
#define NH 8
#define DH 128
#define HKDIM 1024  // NH*DH

static __device__ __forceinline__ f32x4 mfma16(bf16x8 a, bf16x8 b, f32x4 c) {
    return __builtin_amdgcn_mfma_f32_16x16x32_bf16(a, b, c, 0, 0, 0);
}
static __device__ __forceinline__ f32x16 mfma32(bf16x8 a, bf16x8 b, f32x16 c) {
    return __builtin_amdgcn_mfma_f32_32x32x16_bf16(a, b, c, 0, 0, 0);
}

static __device__ __forceinline__ unsigned pk2(float a, float b) {
    bf16x2_t t;
    t[0] = (bf16_t)a;
    t[1] = (bf16_t)b;
    union { bf16x2_t v; unsigned u; } c;
    c.v = t;
    return c.u;
}

// v_permlane32_swap via builtin: r[0] = {a.lo, b.lo}, r[1] = {a.hi, b.hi}
static __device__ __forceinline__ void plswap(unsigned& a, unsigned& b) {
    u32x2 r = __builtin_amdgcn_permlane32_swap(a, b, false, false);
    a = r[0];
    b = r[1];
}

// value of x from lane^32 (pure VALU, no DS)
static __device__ __forceinline__ float swap_partner(float x) {
    u32x2 r = __builtin_amdgcn_permlane32_swap(__float_as_uint(x),
                                               __float_as_uint(x), false, false);
    return __uint_as_float((threadIdx.x & 32) ? r[0] : r[1]);
}

// ---------------------------------------------------------------------------
// Kernel 1: convert inputs to bf16 working layouts (float4-vectorized).
// ---------------------------------------------------------------------------
__global__ __launch_bounds__(256) void convert_kernel(
        const float* __restrict__ x,
        const float* __restrict__ Wk, const float* __restrict__ Wq,
        const float* __restrict__ Wv, const float* __restrict__ Wo,
        bf16_t* __restrict__ xb, bf16_t* __restrict__ w3,
        bf16_t* __restrict__ wo) {
    const int n1 = T_SEQ * BATCH * DH;        // 1048576
    const int n2 = n1 + 3 * HKDIM * DH;       // +393216
    const int n3 = n2 + DH * HKDIM;           // +131072
    const int i = (blockIdx.x * 256 + threadIdx.x) * 4;
    if (i >= n3) return;
    const float* src;
    bf16_t* dst;
    if (i < n1) {
        int d = i & 127, t = (i >> 7) & 1023, b = i >> 17;
        src = x + (t * BATCH + b) * DH + d;
        dst = xb + i;
    } else if (i < n2) {
        int j = i - n1;
        int p = j >> 17;
        const float* W = (p == 0) ? Wk : (p == 1 ? Wq : Wv);
        src = W + (j & 131071);
        dst = w3 + j;
    } else {
        int j = i - n2;
        src = Wo + j;
        dst = wo + j;
    }
    f32x4 v = *(const f32x4*)src;
    bf16x4_t o;
    o[0] = (bf16_t)v[0]; o[1] = (bf16_t)v[1];
    o[2] = (bf16_t)v[2]; o[3] = (bf16_t)v[3];
    *(bf16x4_t*)dst = o;
}

// ---------------------------------------------------------------------------
// Kernel 2: QKV projection (unchanged from r14: full-head blocks, 256B
//   contiguous output rows). Grid dim3(64, 24); p = by>>3, h = by&7.
// ---------------------------------------------------------------------------
__global__ __launch_bounds__(256) void proj_kernel(
        const bf16_t* __restrict__ xb, const bf16_t* __restrict__ w3,
        const float* __restrict__ bk, const float* __restrict__ bq,
        const float* __restrict__ bv,
        bf16_t* __restrict__ kbuf, bf16_t* __restrict__ qbuf,
        bf16_t* __restrict__ vtbuf) {
    const int lane = threadIdx.x & 63;
    const int wave = threadIdx.x >> 6;
    const int lr = lane & 15, lq = lane >> 4;
    const int rm_base = blockIdx.x * 128;
    const int p = blockIdx.y >> 3;       // 0=K, 1=Q, 2=V
    const int h = blockIdx.y & 7;
    const int cb0 = p * 1024 + h * 128;  // global col of this head's d=0
    const int cw0 = h * 128;             // col within projection
    const bool isV = (p == 2);

    __shared__ bf16_t sL[128][136];      // aL[t][d] (K/Q) or vL[d][t] (V)

    // A fragments from xb: 8 loads in flight
    bf16x8 aF[2][4];
#pragma unroll
    for (int rg = 0; rg < 2; ++rg) {
        const int row = rm_base + rg * 64 + wave * 16 + lr;
#pragma unroll
        for (int kc = 0; kc < 4; ++kc)
            aF[rg][kc] = *(const bf16x8*)(xb + (size_t)row * DH + kc * 32 + lq * 8);
    }

    const bf16_t* wbase = w3 + (size_t)(cb0 + lr) * DH + lq * 8;
    bf16x8 kcur[4], knxt[4];
#pragma unroll
    for (int kc = 0; kc < 4; ++kc)
        kcur[kc] = *(const bf16x8*)(wbase + kc * 32);

    const float* bias_kq = (p == 0) ? bk : bq;
    bf16_t* dst = (p == 0) ? kbuf : qbuf;

#pragma unroll
    for (int nc = 0; nc < 8; ++nc) {
        if (nc < 7) {
            const bf16_t* wn = wbase + (size_t)(nc + 1) * 16 * DH;
#pragma unroll
            for (int kc = 0; kc < 4; ++kc)
                knxt[kc] = *(const bf16x8*)(wn + kc * 32);
        }

        f32x4 acc[2] = {{0.f, 0.f, 0.f, 0.f}, {0.f, 0.f, 0.f, 0.f}};
        if (!isV) {
#pragma unroll
            for (int rg = 0; rg < 2; ++rg)
#pragma unroll
                for (int kc = 0; kc < 4; ++kc)
                    acc[rg] = mfma16(kcur[kc], aF[rg][kc], acc[rg]);

            const f32x4 b4 = *(const f32x4*)(bias_kq + cw0 + nc * 16 + lq * 4);
#pragma unroll
            for (int rg = 0; rg < 2; ++rg) {
                bf16x4_t o4;
#pragma unroll
                for (int r = 0; r < 4; ++r)
                    o4[r] = (bf16_t)(acc[rg][r] + b4[r]);
                *(bf16x4_t*)&sL[rg * 64 + wave * 16 + lr][nc * 16 + lq * 4] = o4;
            }
        } else {
#pragma unroll
            for (int rg = 0; rg < 2; ++rg)
#pragma unroll
                for (int kc = 0; kc < 4; ++kc)
                    acc[rg] = mfma16(aF[rg][kc], kcur[kc], acc[rg]);

            const float bias = bv[cw0 + nc * 16 + lr];
#pragma unroll
            for (int rg = 0; rg < 2; ++rg)
#pragma unroll
                for (int r = 0; r < 4; ++r)
                    sL[nc * 16 + lr][rg * 64 + wave * 16 + lq * 4 + r] =
                        (bf16_t)(acc[rg][r] + bias);
        }
        if (nc < 7) {
#pragma unroll
            for (int kc = 0; kc < 4; ++kc) kcur[kc] = knxt[kc];
        }
    }

    __syncthreads();
    const int tid = threadIdx.x;
    if (!isV) {
        const int tr = tid >> 4;            // 0..15
        const int ck = tid & 15;            // 16B chunk
#pragma unroll
        for (int ps = 0; ps < 8; ++ps) {
            const int t_local = ps * 16 + tr;
            const int row = rm_base + t_local;
            const int bb = row >> 10, tt = row & 1023;
            bf16x8 v = *(const bf16x8*)&sL[t_local][ck * 8];
            *(bf16x8*)(dst + ((size_t)(bb * NH + h) * T_SEQ + tt) * DH + ck * 8) = v;
        }
    } else {
        const int dr = tid >> 4;            // 0..15
        const int ck = tid & 15;            // 16B chunk within 128-t row
        const int bb = blockIdx.x >> 3;
        const int t0 = (blockIdx.x & 7) * 128;
#pragma unroll
        for (int ps = 0; ps < 8; ++ps) {
            const int d = ps * 16 + dr;
            bf16x8 v = *(const bf16x8*)&sL[d][ck * 8];
            *(bf16x8*)(vtbuf + ((size_t)(bb * NH + h) * DH + d) * T_SEQ +
                       t0 + ck * 8) = v;
        }
    }
}

// ---------------------------------------------------------------------------
// Kernel 3: flash attention, 128-row i-tile, KVBLK=64, DOUBLE-BUFFERED LDS:
//   one barrier per round (writers target the idle buffer, so the
//   "readers-done" barrier disappears); prefetched global loads get a full
//   compute phase of latency hiding before their ds_write. CU-pairing grid.
// ---------------------------------------------------------------------------
__global__ __launch_bounds__(256, 2) void attn_kernel(
        const bf16_t* __restrict__ kbuf, const bf16_t* __restrict__ qbuf,
        const bf16_t* __restrict__ vtb, bf16_t* __restrict__ obuf) {
    const int bx = blockIdx.x;
    const int T = (bx < 256) ? (7 - (bx >> 6)) : ((bx - 256) >> 6);
    const int bh = bx & 63;
    const int b = bh >> 3, h = bh & 7;
    const int wv = threadIdx.x >> 6;     // i-subtile 0..3
    const int lane = threadIdx.x & 63;
    const int li = lane & 31;
    const int hi = lane >> 5;
    const int i0 = T * 128 + wv * 32;    // wave's first row
    const int cmax = 4 * T + wv;         // last 32-chunk this wave computes
    const int nrounds = 2 * T + 2;       // 64-wide staging rounds (>= 2)

    const bf16_t* Qp = kbuf + (size_t)bh * T_SEQ * DH;  // rows i (key positions)
    const bf16_t* Kp = qbuf + (size_t)bh * T_SEQ * DH;  // cols j (query positions)
    const bf16_t* Vt = vtb + (size_t)bh * DH * T_SEQ;   // [d][t]

    __shared__ bf16_t kL[2][64][136];   // K super-chunks, double-buffered
    __shared__ bf16_t vL[2][128][72];   // V^T super-chunks, double-buffered

    // persistent Q B-fragments: lane: i=li, k = s*16 + hi*8 + e
    bf16x8 qf[8];
#pragma unroll
    for (int s = 0; s < 8; ++s)
        qf[s] = *(const bf16x8*)(Qp + (size_t)(i0 + li) * DH + s * 16 + hi * 8);

    f32x16 oacc[4];
#pragma unroll
    for (int c = 0; c < 4; ++c)
#pragma unroll
        for (int e = 0; e < 16; ++e) oacc[c][e] = 0.f;

    float m = 0.f, l = 0.f;
    const float C = 0.08838834764831845f * 1.4426950408889634f;  // scale*log2e

    // staging decomposition: 64B K + 64B V per thread per round
    const int tid = threadIdx.x;
    const int krow = tid >> 2;            // 0..63
    const int kcol = (tid & 3) * 32;      // 0,32,64,96
    const int vrow = tid >> 1;            // 0..127
    const int vcol = (tid & 1) * 32;      // 0,32
    const bf16_t* kgsrc = Kp + (size_t)krow * DH + kcol;
    const bf16_t* vgsrc = Vt + (size_t)vrow * T_SEQ + vcol;

    // prologue: round 0 -> buf0; issue round 1 loads (nrounds >= 2 always)
    bf16x8 kr[4], vr[4];
#pragma unroll
    for (int i = 0; i < 4; ++i) {
        kr[i] = *(const bf16x8*)(kgsrc + i * 8);
        vr[i] = *(const bf16x8*)(vgsrc + i * 8);
    }
#pragma unroll
    for (int i = 0; i < 4; ++i) {
        *(bf16x8*)&kL[0][krow][kcol + i * 8] = kr[i];
        *(bf16x8*)&vL[0][vrow][vcol + i * 8] = vr[i];
    }
#pragma unroll
    for (int i = 0; i < 4; ++i) {
        kr[i] = *(const bf16x8*)(kgsrc + (size_t)64 * DH + i * 8);
        vr[i] = *(const bf16x8*)(vgsrc + 64 + i * 8);
    }
    __syncthreads();

    for (int rd = 0; rd < nrounds; ++rd) {
        const int cur = rd & 1;

#pragma unroll
        for (int jj = 0; jj < 2; ++jj) {
            const int c32 = rd * 2 + jj;
            if (c32 > cmax) continue;

            // K fragments from LDS
            bf16x8 ka[8];
#pragma unroll
            for (int s = 0; s < 8; ++s)
                ka[s] = *(const bf16x8*)&kL[cur][jj * 32 + li][s * 16 + hi * 8];

            // S^T = K' Q'^T : C[m=j][n=i]
            f32x16 sc;
#pragma unroll
            for (int e = 0; e < 16; ++e) sc[e] = 0.f;
            __builtin_amdgcn_s_setprio(1);
#pragma unroll
            for (int s = 0; s < 8; ++s) sc = mfma32(ka[s], qf[s], sc);
            __builtin_amdgcn_s_setprio(0);

            // scale (+ diagonal causal mask: j > i)
            f32x16 sv;
#pragma unroll
            for (int e = 0; e < 16; ++e) sv[e] = sc[e] * C;
            if (c32 == cmax) {
#pragma unroll
                for (int r = 0; r < 16; ++r) {
                    const int jrow = (r & 3) + 8 * (r >> 2) + 4 * hi;
                    if (jrow > li) sv[r] = -1e30f;
                }
            }

            // row max: in-lane tree + cross-half permlane (no DS)
            float pm = sv[0];
#pragma unroll
            for (int r = 1; r < 16; ++r) pm = fmaxf(pm, sv[r]);
            pm = fmaxf(pm, swap_partner(pm));

            // T13 defer-rescale (log2 domain, THR=8)
            if (!__all(pm <= m + 8.f)) {
                const float mn = fmaxf(m, pm);
                const float f = exp2f(m - mn);
                m = mn;
                l *= f;
#pragma unroll
                for (int cc = 0; cc < 4; ++cc)
#pragma unroll
                    for (int e = 0; e < 16; ++e) oacc[cc][e] *= f;
            }

            // P = 2^(sv - m), pack to bf16 pairs along j
            float ls = 0.f;
            unsigned Wp[8];
#pragma unroll
            for (int q = 0; q < 4; ++q) {
                const float p0 = exp2f(sv[4 * q + 0] - m);
                const float p1 = exp2f(sv[4 * q + 1] - m);
                const float p2 = exp2f(sv[4 * q + 2] - m);
                const float p3 = exp2f(sv[4 * q + 3] - m);
                ls += (p0 + p1) + (p2 + p3);
                Wp[2 * q] = pk2(p0, p1);
                Wp[2 * q + 1] = pk2(p2, p3);
            }
            l += ls;

            // redistribute P into B-fragments: 4 permlane32_swap (pure VALU)
            plswap(Wp[0], Wp[2]);
            plswap(Wp[1], Wp[3]);
            plswap(Wp[4], Wp[6]);
            plswap(Wp[5], Wp[7]);
            union { unsigned u[4]; bf16x8 v; } pb0, pb1;
            pb0.u[0] = Wp[0]; pb0.u[1] = Wp[1]; pb0.u[2] = Wp[2]; pb0.u[3] = Wp[3];
            pb1.u[0] = Wp[4]; pb1.u[1] = Wp[5]; pb1.u[2] = Wp[6]; pb1.u[3] = Wp[7];

            // V fragments from LDS; PV: O^T[d][i] += V^T[d][j] P[j][i]
            bf16x8 va[8];
#pragma unroll
            for (int n = 0; n < 4; ++n) {
                va[2 * n]     = *(const bf16x8*)&vL[cur][li + 32 * n][jj * 32 + hi * 8];
                va[2 * n + 1] = *(const bf16x8*)&vL[cur][li + 32 * n][jj * 32 + hi * 8 + 16];
            }
            __builtin_amdgcn_s_setprio(1);
            oacc[0] = mfma32(va[0], pb0.v, oacc[0]);
            oacc[0] = mfma32(va[1], pb1.v, oacc[0]);
            oacc[1] = mfma32(va[2], pb0.v, oacc[1]);
            oacc[1] = mfma32(va[3], pb1.v, oacc[1]);
            oacc[2] = mfma32(va[4], pb0.v, oacc[2]);
            oacc[2] = mfma32(va[5], pb1.v, oacc[2]);
            oacc[3] = mfma32(va[6], pb0.v, oacc[3]);
            oacc[3] = mfma32(va[7], pb1.v, oacc[3]);
            __builtin_amdgcn_s_setprio(0);
        }

        // stage round rd+1 into the idle buffer; issue loads for rd+2
        if (rd + 1 < nrounds) {
            const int nxt = cur ^ 1;
#pragma unroll
            for (int i = 0; i < 4; ++i) {
                *(bf16x8*)&kL[nxt][krow][kcol + i * 8] = kr[i];
                *(bf16x8*)&vL[nxt][vrow][vcol + i * 8] = vr[i];
            }
            if (rd + 2 < nrounds) {
                const bf16_t* kn = kgsrc + (size_t)(rd + 2) * 64 * DH;
                const bf16_t* vn = vgsrc + (size_t)(rd + 2) * 64;
#pragma unroll
                for (int i = 0; i < 4; ++i) {
                    kr[i] = *(const bf16x8*)(kn + i * 8);
                    vr[i] = *(const bf16x8*)(vn + i * 8);
                }
            }
        }
        __syncthreads();
    }

    // epilogue: normalize, stage O rows in kL (flat 128x136), then write
    // each 256B obuf row with 16 lanes x 16B (full-line bursts).
    const float lfull = l + swap_partner(l);
    const float inv = 1.f / lfull;
    bf16_t* oflat = &kL[0][0][0];        // 128 rows x 136 elems
    const int rl = wv * 32 + li;
#pragma unroll
    for (int c = 0; c < 4; ++c)
#pragma unroll
        for (int q = 0; q < 4; ++q) {
            bf16x4_t o4;
#pragma unroll
            for (int rr = 0; rr < 4; ++rr)
                o4[rr] = (bf16_t)(oacc[c][4 * q + rr] * inv);
            *(bf16x4_t*)(oflat + (size_t)rl * 136 + c * 32 + q * 8 + 4 * hi) = o4;
        }
    __syncthreads();
    {
        const int tr = tid >> 4;   // 0..15
        const int ck = tid & 15;
#pragma unroll
        for (int ps = 0; ps < 8; ++ps) {
            const int rlr = ps * 16 + tr;          // 0..127
            bf16x8 v = *(const bf16x8*)(oflat + (size_t)rlr * 136 + ck * 8);
            const int row = T * 128 + rlr;
            *(bf16x8*)(obuf + ((size_t)b * T_SEQ + row) * HKDIM + h * DH + ck * 8) = v;
        }
    }
}

// ---------------------------------------------------------------------------
// Kernel 4: output projection, split-K over waves. All 8 A-fragments (HBM)
//   loaded upfront: one ~900cy HBM latency instead of 8 serialized chains.
// ---------------------------------------------------------------------------
__global__ __launch_bounds__(256) void outproj_kernel(
        const bf16_t* __restrict__ obuf, const bf16_t* __restrict__ wo,
        const float* __restrict__ bo, float* __restrict__ out) {
    const int lane = threadIdx.x & 63, wave = threadIdx.x >> 6;
    const int lr = lane & 15, lq = lane >> 4;
    const int rm0 = blockIdx.x * 16;
    __shared__ float red[4][8][256];   // [wave][g][lane*4]

    // batch all 8 A-fragments (obuf rows, HBM) before the MFMA loop
    const bf16_t* abase = obuf + (size_t)(rm0 + lr) * HKDIM + wave * 256 + lq * 8;
    bf16x8 aA[8];
#pragma unroll
    for (int k8 = 0; k8 < 8; ++k8)
        aA[k8] = *(const bf16x8*)(abase + k8 * 32);

    f32x4 acc[8];
#pragma unroll
    for (int g = 0; g < 8; ++g) acc[g] = {0.f, 0.f, 0.f, 0.f};
#pragma unroll
    for (int k8 = 0; k8 < 8; ++k8) {
        const int kc = wave * 8 + k8;
#pragma unroll
        for (int g = 0; g < 8; ++g) {
            bf16x8 bF = *(const bf16x8*)(wo + (size_t)(g * 16 + lr) * HKDIM + kc * 32 + lq * 8);
            acc[g] = mfma16(aA[k8], bF, acc[g]);
        }
    }
#pragma unroll
    for (int g = 0; g < 8; ++g)
        *(f32x4*)&red[wave][g][lane * 4] = acc[g];
    __syncthreads();
#pragma unroll
    for (int gi = 0; gi < 2; ++gi) {
        const int g = wave * 2 + gi;
        f32x4 s = *(const f32x4*)&red[0][g][lane * 4];
#pragma unroll
        for (int w = 1; w < 4; ++w) {
            f32x4 t = *(const f32x4*)&red[w][g][lane * 4];
            s[0] += t[0]; s[1] += t[1]; s[2] += t[2]; s[3] += t[3];
        }
        const int col = g * 16 + lr;
        const float bias = bo[col];
#pragma unroll
        for (int r = 0; r < 4; ++r) {
            const int row = rm0 + lq * 4 + r;
            const int bb = row >> 10, tt = row & 1023;
            out[((size_t)tt * BATCH + bb) * DH + col] = s[r] + bias;
        }
    }
}

// ---------------------------------------------------------------------------
extern "C" void kernel_launch(void* const* d_in, const int* in_sizes, int n_in,
                              void* d_out, int out_size, void* d_ws, size_t ws_size,
                              hipStream_t stream) {
    const float* x  = (const float*)d_in[0];
    const float* Wk = (const float*)d_in[1];
    const float* bk = (const float*)d_in[2];
    const float* Wq = (const float*)d_in[3];
    const float* bq = (const float*)d_in[4];
    const float* Wv = (const float*)d_in[5];
    const float* bv = (const float*)d_in[6];
    const float* Wo = (const float*)d_in[7];
    const float* bo = (const float*)d_in[8];
    float* out = (float*)d_out;

    char* ws = (char*)d_ws;
    size_t off = 0;
    bf16_t* xb  = (bf16_t*)(ws + off); off += (size_t)BATCH * T_SEQ * DH * 2;       // 2 MiB
    bf16_t* w3  = (bf16_t*)(ws + off); off += (size_t)3 * HKDIM * DH * 2;           // 0.75 MiB
    bf16_t* wo  = (bf16_t*)(ws + off); off += (size_t)DH * HKDIM * 2;               // 0.25 MiB
    bf16_t* kb  = (bf16_t*)(ws + off); off += (size_t)BATCH * NH * T_SEQ * DH * 2;  // 16 MiB
    bf16_t* qb  = (bf16_t*)(ws + off); off += (size_t)BATCH * NH * T_SEQ * DH * 2;  // 16 MiB
    bf16_t* vtb = (bf16_t*)(ws + off); off += (size_t)BATCH * NH * T_SEQ * DH * 2;  // 16 MiB
    bf16_t* ob  = (bf16_t*)(ws + off); off += (size_t)BATCH * T_SEQ * HKDIM * 2;    // 16 MiB

    convert_kernel<<<1536, 256, 0, stream>>>(x, Wk, Wq, Wv, Wo, xb, w3, wo);
    proj_kernel<<<dim3(64, 24), 256, 0, stream>>>(xb, w3, bk, bq, bv, kb, qb, vtb);
    attn_kernel<<<512, 256, 0, stream>>>(kb, qb, vtb, ob);
    outproj_kernel<<<512, 256, 0, stream>>>(ob, wo, bo, out);
}